// Round 2
// baseline (399.499 us; speedup 1.0000x reference)
//
#include <hip/hip_runtime.h>
#include <hip/hip_bf16.h>

// Fused 3-stage strided conv1d encoder, algebraically composed.
// Three K=6 stride=2 VALID convs on [B,1,16384] compose (linearity) into ONE
// 36-tap stride-8 conv:
//   out[j3] = sum_t Weff[t] * x[8*j3 + t] + Beff,  t in [0,36)
//   Weff[4a+2b+c] = sum w3[a]*w2[b]*w1[c];  Beff = b3 + b2*S3 + b1*S2*S3
// Each thread computes 4 consecutive outputs from a 60-float window
// (15 aligned float4 loads), 36 FMAs per output.
// Roofline: 268 MB read + 33.5 MB write => ~48 us at 6.3 TB/s.

#define L_IN  16384
#define L3    2044
#define KW    6
#define GROUPS (L3 / 4)   // 511 thread-groups per row

__global__ __launch_bounds__(256) void encoder_fused_kernel(
    const float* __restrict__ x,
    const float* __restrict__ w1, const float* __restrict__ b1,
    const float* __restrict__ w2, const float* __restrict__ b2,
    const float* __restrict__ w3, const float* __restrict__ b3,
    float* __restrict__ out)
{
    __shared__ float sW[37];

    const int tx = threadIdx.x;
    // Per-block composite-weight computation (216 products, negligible).
    if (tx < 36) {
        float s = 0.f;
        for (int a = 0; a < KW; ++a) {
            const int rem = tx - 4 * a;
            for (int b = 0; b < KW; ++b) {
                const int c = rem - 2 * b;
                if (c >= 0 && c < KW) s += w3[a] * w2[b] * w1[c];
            }
        }
        sW[tx] = s;
    } else if (tx == 36) {
        float s3 = 0.f, s2 = 0.f;
        for (int i = 0; i < KW; ++i) { s3 += w3[i]; s2 += w2[i]; }
        sW[36] = b3[0] + b2[0] * s3 + b1[0] * s2 * s3;
    }
    __syncthreads();

    const int t = blockIdx.x * blockDim.x + tx;   // 4-output group within row
    const int row = blockIdx.y;
    if (t >= GROUPS) return;
    const int j3 = 4 * t;

    // Copy weights LDS -> VGPRs once (broadcast reads, conflict-free).
    float W[36];
#pragma unroll
    for (int k = 0; k < 36; ++k) W[k] = sW[k];
    const float Beff = sW[36];

    // 60-float window: x[8*j3 .. 8*j3+59], 128B-aligned start.
    const float* xr = x + (size_t)row * L_IN + 8 * (size_t)j3;
    const float4* xv = reinterpret_cast<const float4*>(xr);
    float v[60];
#pragma unroll
    for (int i = 0; i < 15; ++i) {
        float4 q = xv[i];
        v[4 * i + 0] = q.x;
        v[4 * i + 1] = q.y;
        v[4 * i + 2] = q.z;
        v[4 * i + 3] = q.w;
    }

    float acc[4];
#pragma unroll
    for (int i = 0; i < 4; ++i) {
        float s = Beff;
#pragma unroll
        for (int k = 0; k < 36; ++k) s = fmaf(W[k], v[8 * i + k], s);
        acc[i] = s;
    }

    // Aligned float4 store: row*L3 + j3 elements; L3*4B = 511*16B.
    float4 o;
    o.x = acc[0]; o.y = acc[1]; o.z = acc[2]; o.w = acc[3];
    *reinterpret_cast<float4*>(out + (size_t)row * L3 + j3) = o;
}

extern "C" void kernel_launch(void* const* d_in, const int* in_sizes, int n_in,
                              void* d_out, int out_size, void* d_ws, size_t ws_size,
                              hipStream_t stream) {
    const float* x  = (const float*)d_in[0];
    const float* w1 = (const float*)d_in[1];
    const float* b1 = (const float*)d_in[2];
    const float* w2 = (const float*)d_in[3];
    const float* b2 = (const float*)d_in[4];
    const float* w3 = (const float*)d_in[5];
    const float* b3 = (const float*)d_in[6];
    float* out = (float*)d_out;

    const int B = in_sizes[0] / L_IN;  // 4096

    dim3 block(256);
    dim3 grid((GROUPS + 255) / 256, B);  // (2, 4096)
    encoder_fused_kernel<<<grid, block, 0, stream>>>(x, w1, b1, w2, b2, w3, b3, out);
}

// Round 3
// 396.414 us; speedup vs baseline: 1.0078x; 1.0078x over previous
//
#include <hip/hip_runtime.h>
#include <hip/hip_bf16.h>

// Fused 3-stage strided conv1d encoder, algebraically composed.
// Three K=6 stride=2 VALID convs compose (linearity) into ONE 36-tap
// stride-8 conv:  out[j3] = sum_t Weff[t]*x[8*j3+t] + Beff.
// Kernel A (1 block): compute Weff[36], Beff into d_ws.
// Kernel B: each thread computes 4 consecutive outputs from a 60-float
// window (15 aligned float4 loads). Weights are wave-uniform ->
// readfirstlane into SGPRs (FMA with SGPR src, frees ~36 VGPRs).
// Roofline: 268 MB read + 33.5 MB write => ~48 us at 6.3 TB/s.

#define L_IN  16384
#define L3    2044
#define KW    6
#define GROUPS (L3 / 4)   // 511 4-output groups per row

__global__ __launch_bounds__(64) void encoder_weights_kernel(
    const float* __restrict__ w1, const float* __restrict__ b1,
    const float* __restrict__ w2, const float* __restrict__ b2,
    const float* __restrict__ w3, const float* __restrict__ b3,
    float* __restrict__ wb)   // wb[0..35] = Weff, wb[36] = Beff
{
    const int tx = threadIdx.x;
    if (tx < 36) {
        float s = 0.f;
        for (int a = 0; a < KW; ++a) {
            const int rem = tx - 4 * a;
            for (int b = 0; b < KW; ++b) {
                const int c = rem - 2 * b;
                if (c >= 0 && c < KW) s += w3[a] * w2[b] * w1[c];
            }
        }
        wb[tx] = s;
    } else if (tx == 36) {
        float s3 = 0.f, s2 = 0.f;
        for (int i = 0; i < KW; ++i) { s3 += w3[i]; s2 += w2[i]; }
        wb[36] = b3[0] + b2[0] * s3 + b1[0] * s2 * s3;
    }
}

__device__ __forceinline__ float uniform_load(const float* p) {
    // all lanes read the same address; force the value into an SGPR
    return __uint_as_float(__builtin_amdgcn_readfirstlane(__float_as_uint(*p)));
}

__global__ __launch_bounds__(256) void encoder_main_kernel(
    const float* __restrict__ x,
    const float* __restrict__ wb,
    float* __restrict__ out)
{
    const int t = blockIdx.x * blockDim.x + threadIdx.x;  // 4-output group
    const int row = blockIdx.y;
    if (t >= GROUPS) return;
    const int j3 = 4 * t;

    // Wave-uniform weights -> SGPRs.
    float W[36];
#pragma unroll
    for (int k = 0; k < 36; ++k) W[k] = uniform_load(wb + k);
    const float Beff = uniform_load(wb + 36);

    // 60-float window: x[8*j3 .. 8*j3+59], 32B-aligned start.
    const float* xr = x + (size_t)row * L_IN + 8 * (size_t)j3;
    const float4* xv = reinterpret_cast<const float4*>(xr);
    float v[60];
#pragma unroll
    for (int i = 0; i < 15; ++i) {
        float4 q = xv[i];
        v[4 * i + 0] = q.x;
        v[4 * i + 1] = q.y;
        v[4 * i + 2] = q.z;
        v[4 * i + 3] = q.w;
    }

    float acc[4];
#pragma unroll
    for (int i = 0; i < 4; ++i) {
        float s = Beff;
#pragma unroll
        for (int k = 0; k < 36; ++k) s = fmaf(W[k], v[8 * i + k], s);
        acc[i] = s;
    }

    float4 o;
    o.x = acc[0]; o.y = acc[1]; o.z = acc[2]; o.w = acc[3];
    *reinterpret_cast<float4*>(out + (size_t)row * L3 + j3) = o;
}

extern "C" void kernel_launch(void* const* d_in, const int* in_sizes, int n_in,
                              void* d_out, int out_size, void* d_ws, size_t ws_size,
                              hipStream_t stream) {
    const float* x  = (const float*)d_in[0];
    const float* w1 = (const float*)d_in[1];
    const float* b1 = (const float*)d_in[2];
    const float* w2 = (const float*)d_in[3];
    const float* b2 = (const float*)d_in[4];
    const float* w3 = (const float*)d_in[5];
    const float* b3 = (const float*)d_in[6];
    float* out = (float*)d_out;
    float* wb  = (float*)d_ws;   // 37 floats of scratch

    const int B = in_sizes[0] / L_IN;  // 4096

    encoder_weights_kernel<<<1, 64, 0, stream>>>(w1, b1, w2, b2, w3, b3, wb);

    dim3 block(256);
    dim3 grid((GROUPS + 255) / 256, B);  // (2, 4096)
    encoder_main_kernel<<<grid, block, 0, stream>>>(x, wb, out);
}

// Round 4
// 380.261 us; speedup vs baseline: 1.0506x; 1.0425x over previous
//
#include <hip/hip_runtime.h>
#include <hip/hip_bf16.h>

// Fused 3-stage strided conv1d encoder, algebraically composed into ONE
// 36-tap stride-8 conv:  out[j3] = sum_t Weff[t]*x[8*j3+t] + Beff.
//
// R4: coalesced global->LDS staging. One block per row (16384 floats):
//  - 256 threads stage the row with 16 perfectly-coalesced float4 loads each
//  - LDS padded +4 floats per 64 (preserves 16B alignment of all float4
//    accesses; makes the 64-float read lane-stride map to bank stride 4 ->
//    8 lanes tile all 32 banks -> conflict-free b128 phases)
//  - thread t computes outputs 8t..8t+7 via a 36-float register sliding
//    window (9 initial + 2/step ds_read_b128), dense float4 stores.
// Weights are wave-uniform -> readfirstlane into SGPRs.
// Roofline: 268 MB read + 33.5 MB write => ~45 us at 6.7 TB/s achieved.

#define L_IN  16384
#define L3    2044
#define KW    6

// padded LDS slot: +4 floats per 64-float group (keeps 16B alignment)
__device__ __forceinline__ int pad_slot(int g) { return g + 4 * (g >> 6); }

// max slot touched: g up to 64*255+8*7+35 = 16411 -> slot 17435; round up
#define LDS_FLOATS 17440

__global__ __launch_bounds__(64) void encoder_weights_kernel(
    const float* __restrict__ w1, const float* __restrict__ b1,
    const float* __restrict__ w2, const float* __restrict__ b2,
    const float* __restrict__ w3, const float* __restrict__ b3,
    float* __restrict__ wb)   // wb[0..35] = Weff, wb[36] = Beff
{
    const int tx = threadIdx.x;
    if (tx < 36) {
        float s = 0.f;
        for (int a = 0; a < KW; ++a) {
            const int rem = tx - 4 * a;
            for (int b = 0; b < KW; ++b) {
                const int c = rem - 2 * b;
                if (c >= 0 && c < KW) s += w3[a] * w2[b] * w1[c];
            }
        }
        wb[tx] = s;
    } else if (tx == 36) {
        float s3 = 0.f, s2 = 0.f;
        for (int i = 0; i < KW; ++i) { s3 += w3[i]; s2 += w2[i]; }
        wb[36] = b3[0] + b2[0] * s3 + b1[0] * s2 * s3;
    }
}

__device__ __forceinline__ float uniform_load(const float* p) {
    return __uint_as_float(__builtin_amdgcn_readfirstlane(__float_as_uint(*p)));
}

__global__ __launch_bounds__(256, 2) void encoder_main_kernel(
    const float* __restrict__ x,
    const float* __restrict__ wb,
    float* __restrict__ out)
{
    __shared__ float s[LDS_FLOATS];

    const int t   = threadIdx.x;
    const int row = blockIdx.x;

    // ---- stage row -> LDS, perfectly coalesced ----
    const float* xr = x + (size_t)row * L_IN;
#pragma unroll
    for (int i = 0; i < 16; ++i) {
        const int f = 4 * (t + 256 * i);            // contiguous across lanes
        float4 q = *reinterpret_cast<const float4*>(xr + f);
        *reinterpret_cast<float4*>(&s[pad_slot(f)]) = q;
    }

    // weights -> SGPRs (overlaps with staging latency)
    float W[36];
#pragma unroll
    for (int k = 0; k < 36; ++k) W[k] = uniform_load(wb + k);
    const float Beff = uniform_load(wb + 36);

    __syncthreads();

    // ---- compute 8 outputs per thread with sliding 36-float window ----
    const int g0 = 64 * t;
    float v[36];
#pragma unroll
    for (int j = 0; j < 9; ++j)
        *reinterpret_cast<float4*>(&v[4 * j]) =
            *reinterpret_cast<const float4*>(&s[pad_slot(g0 + 4 * j)]);

    float r[8];
#pragma unroll
    for (int i = 0; i < 8; ++i) {
        if (i > 0) {
            // shift window by 8, pull in 8 new floats (2 x b128)
#pragma unroll
            for (int k = 0; k < 28; ++k) v[k] = v[k + 8];
            *reinterpret_cast<float4*>(&v[28]) =
                *reinterpret_cast<const float4*>(&s[pad_slot(g0 + 8 * i + 28)]);
            *reinterpret_cast<float4*>(&v[32]) =
                *reinterpret_cast<const float4*>(&s[pad_slot(g0 + 8 * i + 32)]);
        }
        float acc = Beff;
#pragma unroll
        for (int k = 0; k < 36; ++k) acc = fmaf(W[k], v[k], acc);
        r[i] = acc;
    }

    // ---- dense float4 stores: out[row, 8t..8t+7] ----
    float* orow = out + (size_t)row * L3 + 8 * t;
    float4 o0; o0.x = r[0]; o0.y = r[1]; o0.z = r[2]; o0.w = r[3];
    *reinterpret_cast<float4*>(orow) = o0;                 // 8t+3 <= 2043 always
    if (8 * t + 4 < L3) {                                  // skip for t=255 tail
        float4 o1; o1.x = r[4]; o1.y = r[5]; o1.z = r[6]; o1.w = r[7];
        *reinterpret_cast<float4*>(orow + 4) = o1;
    }
}

extern "C" void kernel_launch(void* const* d_in, const int* in_sizes, int n_in,
                              void* d_out, int out_size, void* d_ws, size_t ws_size,
                              hipStream_t stream) {
    const float* x  = (const float*)d_in[0];
    const float* w1 = (const float*)d_in[1];
    const float* b1 = (const float*)d_in[2];
    const float* w2 = (const float*)d_in[3];
    const float* b2 = (const float*)d_in[4];
    const float* w3 = (const float*)d_in[5];
    const float* b3 = (const float*)d_in[6];
    float* out = (float*)d_out;
    float* wb  = (float*)d_ws;   // 37 floats of scratch

    const int B = in_sizes[0] / L_IN;  // 4096

    encoder_weights_kernel<<<1, 64, 0, stream>>>(w1, b1, w2, b2, w3, b3, wb);
    encoder_main_kernel<<<B, 256, 0, stream>>>(x, wb, out);
}